// Round 1
// baseline (2981.484 us; speedup 1.0000x reference)
//
#include <hip/hip_runtime.h>
#include <hip/hip_fp16.h>

typedef _Float16 f16;
typedef _Float16 half8 __attribute__((ext_vector_type(8)));
typedef _Float16 half4 __attribute__((ext_vector_type(4)));
typedef float f32x4_t __attribute__((ext_vector_type(4)));
typedef unsigned int uint;

#define IN_DIM 512
#define H_DIM 1024
#define OUT_DIM 512
#define NBATCH 64
#define NSEQ 512
#define NGROUP 4
#define MB 16      // batch rows per group
#define WPG 16     // workgroups per group (j-split)
#define NJ 64      // j columns per workgroup

// ---------------- f32 -> f16 conversion ----------------
__global__ __launch_bounds__(256) void cvt_f32_f16_k(const float* __restrict__ src,
                                                     f16* __restrict__ dst, int n) {
  int i = (blockIdx.x * 256 + threadIdx.x) * 4;
  if (i + 3 < n) {
    float4 v = *(const float4*)(src + i);
    half4 h;
    h[0] = (f16)v.x; h[1] = (f16)v.y; h[2] = (f16)v.z; h[3] = (f16)v.w;
    *(half4*)(dst + i) = h;
  }
}

__global__ __launch_bounds__(256) void bias_sum_k(const float* __restrict__ a,
                                                  const float* __restrict__ b,
                                                  float* __restrict__ o) {
  int i = blockIdx.x * 256 + threadIdx.x;
  if (i < H_DIM) o[i] = a[i] + b[i];
}

// ---------------- xp = x @ W_ih^T + (b_ih + b_hh), stored [S][B][H] f16 ----------------
// 128x128 tile, BK=32, 4 waves (each 64x64), f32->f16 convert during staging.
__global__ __launch_bounds__(256) void xp_gemm_k(
    const float* __restrict__ x, const float* __restrict__ wih,
    const float* __restrict__ bsum, f16* __restrict__ xp2)
{
  __shared__ f16 Alds[128 * 32];
  __shared__ f16 Blds[128 * 32];
  const int tid = threadIdx.x;
  const int l = tid & 63;
  const int w = tid >> 6;
  const int r0 = blockIdx.x * 128;   // rows r = b*512 + s
  const int n0 = blockIdx.y * 128;   // h columns
  const int wm = (w >> 1) << 6;
  const int wn = (w & 1) << 6;
  const int srow = tid >> 1;
  const int scol = (tid & 1) << 4;
  const float* ax = x   + (size_t)(r0 + srow) * IN_DIM + scol;
  const float* bw = wih + (size_t)(n0 + srow) * IN_DIM + scol;
  const uint swz  = (uint)(srow & 7) << 4;
  const uint soff = (uint)srow * 64 + (uint)(tid & 1) * 32;
  char* Ab = (char*)Alds;
  char* Bb = (char*)Blds;

  f32x4_t acc[4][4];
  f32x4_t zv; zv[0] = 0.f; zv[1] = 0.f; zv[2] = 0.f; zv[3] = 0.f;
#pragma unroll
  for (int i = 0; i < 4; ++i)
#pragma unroll
    for (int j = 0; j < 4; ++j) acc[i][j] = zv;

  for (int k0 = 0; k0 < IN_DIM; k0 += 32) {
    float4 a0 = *(const float4*)(ax + k0);
    float4 a1 = *(const float4*)(ax + k0 + 4);
    float4 a2 = *(const float4*)(ax + k0 + 8);
    float4 a3 = *(const float4*)(ax + k0 + 12);
    float4 c0 = *(const float4*)(bw + k0);
    float4 c1 = *(const float4*)(bw + k0 + 4);
    float4 c2 = *(const float4*)(bw + k0 + 8);
    float4 c3 = *(const float4*)(bw + k0 + 12);
    __syncthreads();   // previous iteration's ds_reads done before overwrite
    half8 pa0, pa1, pb0, pb1;
    pa0[0]=(f16)a0.x; pa0[1]=(f16)a0.y; pa0[2]=(f16)a0.z; pa0[3]=(f16)a0.w;
    pa0[4]=(f16)a1.x; pa0[5]=(f16)a1.y; pa0[6]=(f16)a1.z; pa0[7]=(f16)a1.w;
    pa1[0]=(f16)a2.x; pa1[1]=(f16)a2.y; pa1[2]=(f16)a2.z; pa1[3]=(f16)a2.w;
    pa1[4]=(f16)a3.x; pa1[5]=(f16)a3.y; pa1[6]=(f16)a3.z; pa1[7]=(f16)a3.w;
    pb0[0]=(f16)c0.x; pb0[1]=(f16)c0.y; pb0[2]=(f16)c0.z; pb0[3]=(f16)c0.w;
    pb0[4]=(f16)c1.x; pb0[5]=(f16)c1.y; pb0[6]=(f16)c1.z; pb0[7]=(f16)c1.w;
    pb1[0]=(f16)c2.x; pb1[1]=(f16)c2.y; pb1[2]=(f16)c2.z; pb1[3]=(f16)c2.w;
    pb1[4]=(f16)c3.x; pb1[5]=(f16)c3.y; pb1[6]=(f16)c3.z; pb1[7]=(f16)c3.w;
    *(half8*)(Ab + (soff ^ swz)) = pa0;
    *(half8*)(Ab + ((soff + 16) ^ swz)) = pa1;
    *(half8*)(Bb + (soff ^ swz)) = pb0;
    *(half8*)(Bb + ((soff + 16) ^ swz)) = pb1;
    __syncthreads();
    half8 af[4], bf[4];
#pragma unroll
    for (int mt = 0; mt < 4; ++mt) {
      uint rr = (uint)(wm + mt * 16 + (l & 15));
      uint off = rr * 64 + ((uint)(l >> 4) << 4);
      af[mt] = *(const half8*)(Ab + (off ^ ((rr & 7) << 4)));
    }
#pragma unroll
    for (int nt = 0; nt < 4; ++nt) {
      uint rr = (uint)(wn + nt * 16 + (l & 15));
      uint off = rr * 64 + ((uint)(l >> 4) << 4);
      bf[nt] = *(const half8*)(Bb + (off ^ ((rr & 7) << 4)));
    }
#pragma unroll
    for (int mt = 0; mt < 4; ++mt)
#pragma unroll
      for (int nt = 0; nt < 4; ++nt)
        acc[mt][nt] = __builtin_amdgcn_mfma_f32_16x16x32_f16(af[mt], bf[nt], acc[mt][nt], 0, 0, 0);
  }

  // epilogue: C row r=(b*512+s) -> xp2[s][b][n], add bias, cast f16
#pragma unroll
  for (int nt = 0; nt < 4; ++nt) {
    const int n = n0 + wn + nt * 16 + (l & 15);
    const float bv = bsum[n];
#pragma unroll
    for (int mt = 0; mt < 4; ++mt) {
#pragma unroll
      for (int i = 0; i < 4; ++i) {
        int r = r0 + wm + mt * 16 + ((l >> 4) << 2) + i;
        int s = r & (NSEQ - 1);
        int b = r >> 9;
        xp2[((size_t)s * NBATCH + b) * H_DIM + n] = (f16)(acc[mt][nt][i] + bv);
      }
    }
  }
}

// ---------------- persistent recurrent scan ----------------
// 64 WGs = 4 batch-groups x 16 j-slices. Each wave holds its W_hh slice
// (16 j-rows x 1024 k, f16) persistently in 128 VGPRs. h staged via LDS.
// One device-scope counter barrier per group per step; h double-buffered.
__global__ __launch_bounds__(256) void rnn_scan_k(
    const f16* __restrict__ whh2, const f16* __restrict__ xp2,
    f16* __restrict__ hbuf, uint* __restrict__ cnt)
{
  __shared__ f16 hlds[MB * H_DIM];   // 32 KB, XOR-swizzled
  const int tid = threadIdx.x;
  const int l   = tid & 63;
  const int w   = tid >> 6;
  const int bid = blockIdx.x;        // 0..63
  const int xcd = bid & 7;           // XCD-locality heuristic (perf only)
  const int g    = xcd >> 1;         // batch group 0..3 (2 XCDs per group)
  const int slot = ((bid >> 3) << 1) | (xcd & 1);  // j-slice 0..15
  const int j0   = slot * NJ + w * 16;             // this wave's global j base
  const int bcol  = l & 15;
  const int brow0 = (l >> 4) << 2;

  // persistent W fragments: lane l row (j0+bcol), k = kt*32 + 8*(l>>4) + i
  half8 wf[32];
  {
    const f16* wp = whh2 + (size_t)(j0 + bcol) * H_DIM + ((l >> 4) << 3);
#pragma unroll
    for (int kt = 0; kt < 32; ++kt) wf[kt] = *(const half8*)(wp + kt * 32);
  }

  f16* hb0 = hbuf + (size_t)g * (2 * MB * H_DIM);
  uint* gcnt = cnt + g * NSEQ;
  const uint roff = (uint)(l & 15) * 2048 + ((uint)(l >> 4) << 4);
  const uint rswz = ((uint)(l & 15) & 7) << 4;
  char* hldsc = (char*)hlds;

  for (int t = 0; t < NSEQ; ++t) {
    const f16* hcur = hb0 + (t & 1) * (MB * H_DIM);
    f16*       hnxt = hb0 + ((t + 1) & 1) * (MB * H_DIM);

    // prefetch xp_t (independent of h -> overlaps barrier spin)
    const f16* xpb = xp2 + ((size_t)t * NBATCH + g * MB + brow0) * H_DIM + (j0 + bcol);
    f16 x0 = xpb[0];
    f16 x1 = xpb[H_DIM];
    f16 x2 = xpb[2 * H_DIM];
    f16 x3 = xpb[3 * H_DIM];

    if (t > 0 && tid == 0) {
      while (__hip_atomic_load(&gcnt[t - 1], __ATOMIC_RELAXED, __HIP_MEMORY_SCOPE_AGENT) < WPG) {}
    }
    __syncthreads();
    if (t > 0) __builtin_amdgcn_fence(__ATOMIC_ACQUIRE, "agent");

    // stage h -> LDS (coalesced global, swizzled LDS writes)
#pragma unroll
    for (int q = 0; q < 8; ++q) {
      uint boff = (uint)(q * 256 + tid) * 16;
      uint4 v = *(const uint4*)((const char*)hcur + boff);
      uint row = boff >> 11;
      *(uint4*)(hldsc + (boff ^ ((row & 7) << 4))) = v;
    }
    __syncthreads();

    f32x4_t acc;
    acc[0] = (float)x0; acc[1] = (float)x1; acc[2] = (float)x2; acc[3] = (float)x3;
#pragma unroll
    for (int kt = 0; kt < 32; ++kt) {
      half8 af = *(const half8*)(hldsc + ((roff + (uint)kt * 64) ^ rswz));
      acc = __builtin_amdgcn_mfma_f32_16x16x32_f16(af, wf[kt], acc, 0, 0, 0);
    }

    // tanh(pre) = 1 - 2/(e^{2x}+1)  (overflow-safe), store f16
    f16* hp = hnxt + (size_t)brow0 * H_DIM + (j0 + bcol);
#pragma unroll
    for (int i = 0; i < 4; ++i) {
      float pre = acc[i];
      float e = __expf(2.0f * pre);
      float th = 1.0f - 2.0f / (e + 1.0f);
      hp[(size_t)i * H_DIM] = (f16)th;
    }

    __syncthreads();   // all waves' stores drained (vmcnt(0) before s_barrier)
    if (tid == 0) {
      __hip_atomic_fetch_add(&gcnt[t], 1u, __ATOMIC_RELEASE, __HIP_MEMORY_SCOPE_AGENT);
    }
  }
}

// ---------------- out = h_final @ W_fc^T + b_fc ----------------
__global__ __launch_bounds__(64) void fc_out_k(
    const f16* __restrict__ hbuf, const f16* __restrict__ wfc2,
    const float* __restrict__ bfc, float* __restrict__ out)
{
  const int l = threadIdx.x;
  const int wg = blockIdx.x;            // 0..127
  const int m0 = wg & 3;                // batch group (16-aligned b tile)
  const int n0 = (wg >> 2) << 4;        // output col base
  const f16* ap = hbuf + (size_t)m0 * (2 * MB * H_DIM)   // buf0 = final h
                  + (size_t)(l & 15) * H_DIM + ((l >> 4) << 3);
  const f16* bp = wfc2 + (size_t)(n0 + (l & 15)) * H_DIM + ((l >> 4) << 3);
  f32x4_t acc;
  float bv = bfc[n0 + (l & 15)];
  acc[0] = bv; acc[1] = bv; acc[2] = bv; acc[3] = bv;
#pragma unroll
  for (int kt = 0; kt < 32; ++kt) {
    half8 a = *(const half8*)(ap + kt * 32);
    half8 b = *(const half8*)(bp + kt * 32);
    acc = __builtin_amdgcn_mfma_f32_16x16x32_f16(a, b, acc, 0, 0, 0);
  }
  const int b0 = (m0 << 4) + ((l >> 4) << 2);
  const int o  = n0 + (l & 15);
#pragma unroll
  for (int i = 0; i < 4; ++i) out[(size_t)(b0 + i) * OUT_DIM + o] = acc[i];
}

// ---------------- launch ----------------
extern "C" void kernel_launch(void* const* d_in, const int* in_sizes, int n_in,
                              void* d_out, int out_size, void* d_ws, size_t ws_size,
                              hipStream_t stream) {
  const float* x   = (const float*)d_in[0];
  const float* wih = (const float*)d_in[1];
  const float* whh = (const float*)d_in[2];
  const float* bih = (const float*)d_in[3];
  const float* bhh = (const float*)d_in[4];
  const float* wfc = (const float*)d_in[5];
  const float* bfc = (const float*)d_in[6];
  float* out = (float*)d_out;
  char* ws = (char*)d_ws;

  // workspace layout (~70.4 MB total)
  f16*   xp2  = (f16*)(ws);                                  // 64 MB  [S][B][H] f16
  f16*   whh2 = (f16*)(ws + (size_t)(64 << 20));             // 2 MB
  f16*   wfc2 = (f16*)(ws + (size_t)(66 << 20));             // 1 MB
  float* bsum = (float*)(ws + (size_t)(67 << 20));           // 4 KB
  f16*   hbuf = (f16*)(ws + (size_t)(67 << 20) + 65536);     // 256 KB [4][2][16][1024]
  uint*  cnt  = (uint*)(ws + (size_t)(67 << 20) + 65536 + 262144); // 8 KB [4][512]

  // zero h double-buffers (initial h=0) + barrier counters, every call
  hipMemsetAsync(hbuf, 0, 262144 + 8192, stream);

  hipLaunchKernelGGL(cvt_f32_f16_k, dim3(1024), dim3(256), 0, stream, whh, whh2, H_DIM * H_DIM);
  hipLaunchKernelGGL(cvt_f32_f16_k, dim3(512),  dim3(256), 0, stream, wfc, wfc2, OUT_DIM * H_DIM);
  hipLaunchKernelGGL(bias_sum_k,    dim3(4),    dim3(256), 0, stream, bih, bhh, bsum);
  hipLaunchKernelGGL(xp_gemm_k,     dim3(256, 8), dim3(256), 0, stream, x, wih, bsum, xp2);
  hipLaunchKernelGGL(rnn_scan_k,    dim3(64),   dim3(256), 0, stream, whh2, xp2, hbuf, cnt);
  hipLaunchKernelGGL(fc_out_k,      dim3(128),  dim3(64),  0, stream, hbuf, wfc2, bfc, out);
}

// Round 2
// 1630.620 us; speedup vs baseline: 1.8284x; 1.8284x over previous
//
#include <hip/hip_runtime.h>
#include <hip/hip_fp16.h>

typedef _Float16 f16;
typedef _Float16 half8 __attribute__((ext_vector_type(8)));
typedef _Float16 half4 __attribute__((ext_vector_type(4)));
typedef float f32x4_t __attribute__((ext_vector_type(4)));
typedef unsigned int uint;
typedef unsigned int uint32x4 __attribute__((ext_vector_type(4)));

#define IN_DIM 512
#define H_DIM 1024
#define OUT_DIM 512
#define NBATCH 64
#define NSEQ 512
#define NGROUP 4
#define MB 16      // batch rows per group
#define WPG 16     // workgroups per group (j-split)
#define NJ 64      // j columns per workgroup

// ---------------- f32 -> f16 conversion ----------------
__global__ __launch_bounds__(256) void cvt_f32_f16_k(const float* __restrict__ src,
                                                     f16* __restrict__ dst, int n) {
  int i = (blockIdx.x * 256 + threadIdx.x) * 4;
  if (i + 3 < n) {
    float4 v = *(const float4*)(src + i);
    half4 h;
    h[0] = (f16)v.x; h[1] = (f16)v.y; h[2] = (f16)v.z; h[3] = (f16)v.w;
    *(half4*)(dst + i) = h;
  }
}

__global__ __launch_bounds__(256) void bias_sum_k(const float* __restrict__ a,
                                                  const float* __restrict__ b,
                                                  float* __restrict__ o) {
  int i = blockIdx.x * 256 + threadIdx.x;
  if (i < H_DIM) o[i] = a[i] + b[i];
}

// ---------------- xp = x @ W_ih^T + (b_ih + b_hh), stored [S][B][H] f16 ----------------
__global__ __launch_bounds__(256) void xp_gemm_k(
    const float* __restrict__ x, const float* __restrict__ wih,
    const float* __restrict__ bsum, f16* __restrict__ xp2)
{
  __shared__ f16 Alds[128 * 32];
  __shared__ f16 Blds[128 * 32];
  const int tid = threadIdx.x;
  const int l = tid & 63;
  const int w = tid >> 6;
  const int r0 = blockIdx.x * 128;   // rows r = b*512 + s
  const int n0 = blockIdx.y * 128;   // h columns
  const int wm = (w >> 1) << 6;
  const int wn = (w & 1) << 6;
  const int srow = tid >> 1;
  const int scol = (tid & 1) << 4;
  const float* ax = x   + (size_t)(r0 + srow) * IN_DIM + scol;
  const float* bw = wih + (size_t)(n0 + srow) * IN_DIM + scol;
  const uint swz  = (uint)(srow & 7) << 4;
  const uint soff = (uint)srow * 64 + (uint)(tid & 1) * 32;
  char* Ab = (char*)Alds;
  char* Bb = (char*)Blds;

  f32x4_t acc[4][4];
  f32x4_t zv; zv[0] = 0.f; zv[1] = 0.f; zv[2] = 0.f; zv[3] = 0.f;
#pragma unroll
  for (int i = 0; i < 4; ++i)
#pragma unroll
    for (int j = 0; j < 4; ++j) acc[i][j] = zv;

  for (int k0 = 0; k0 < IN_DIM; k0 += 32) {
    float4 a0 = *(const float4*)(ax + k0);
    float4 a1 = *(const float4*)(ax + k0 + 4);
    float4 a2 = *(const float4*)(ax + k0 + 8);
    float4 a3 = *(const float4*)(ax + k0 + 12);
    float4 c0 = *(const float4*)(bw + k0);
    float4 c1 = *(const float4*)(bw + k0 + 4);
    float4 c2 = *(const float4*)(bw + k0 + 8);
    float4 c3 = *(const float4*)(bw + k0 + 12);
    __syncthreads();
    half8 pa0, pa1, pb0, pb1;
    pa0[0]=(f16)a0.x; pa0[1]=(f16)a0.y; pa0[2]=(f16)a0.z; pa0[3]=(f16)a0.w;
    pa0[4]=(f16)a1.x; pa0[5]=(f16)a1.y; pa0[6]=(f16)a1.z; pa0[7]=(f16)a1.w;
    pa1[0]=(f16)a2.x; pa1[1]=(f16)a2.y; pa1[2]=(f16)a2.z; pa1[3]=(f16)a2.w;
    pa1[4]=(f16)a3.x; pa1[5]=(f16)a3.y; pa1[6]=(f16)a3.z; pa1[7]=(f16)a3.w;
    pb0[0]=(f16)c0.x; pb0[1]=(f16)c0.y; pb0[2]=(f16)c0.z; pb0[3]=(f16)c0.w;
    pb0[4]=(f16)c1.x; pb0[5]=(f16)c1.y; pb0[6]=(f16)c1.z; pb0[7]=(f16)c1.w;
    pb1[0]=(f16)c2.x; pb1[1]=(f16)c2.y; pb1[2]=(f16)c2.z; pb1[3]=(f16)c2.w;
    pb1[4]=(f16)c3.x; pb1[5]=(f16)c3.y; pb1[6]=(f16)c3.z; pb1[7]=(f16)c3.w;
    *(half8*)(Ab + (soff ^ swz)) = pa0;
    *(half8*)(Ab + ((soff + 16) ^ swz)) = pa1;
    *(half8*)(Bb + (soff ^ swz)) = pb0;
    *(half8*)(Bb + ((soff + 16) ^ swz)) = pb1;
    __syncthreads();
    half8 af[4], bf[4];
#pragma unroll
    for (int mt = 0; mt < 4; ++mt) {
      uint rr = (uint)(wm + mt * 16 + (l & 15));
      uint off = rr * 64 + ((uint)(l >> 4) << 4);
      af[mt] = *(const half8*)(Ab + (off ^ ((rr & 7) << 4)));
    }
#pragma unroll
    for (int nt = 0; nt < 4; ++nt) {
      uint rr = (uint)(wn + nt * 16 + (l & 15));
      uint off = rr * 64 + ((uint)(l >> 4) << 4);
      bf[nt] = *(const half8*)(Bb + (off ^ ((rr & 7) << 4)));
    }
#pragma unroll
    for (int mt = 0; mt < 4; ++mt)
#pragma unroll
      for (int nt = 0; nt < 4; ++nt)
        acc[mt][nt] = __builtin_amdgcn_mfma_f32_16x16x32_f16(af[mt], bf[nt], acc[mt][nt], 0, 0, 0);
  }

#pragma unroll
  for (int nt = 0; nt < 4; ++nt) {
    const int n = n0 + wn + nt * 16 + (l & 15);
    const float bv = bsum[n];
#pragma unroll
    for (int mt = 0; mt < 4; ++mt) {
#pragma unroll
      for (int i = 0; i < 4; ++i) {
        int r = r0 + wm + mt * 16 + ((l >> 4) << 2) + i;
        int s = r & (NSEQ - 1);
        int b = r >> 9;
        xp2[((size_t)s * NBATCH + b) * H_DIM + n] = (f16)(acc[mt][nt][i] + bv);
      }
    }
  }
}

// ---------------- persistent recurrent scan (fence-free L3 handshake) ----------------
// 64 WGs = 4 batch-groups x 16 j-slices; wave holds 16x1024 f16 W_hh slice in
// 128 VGPRs. All cross-WG data moves via L2-bypassing (sc0 sc1 / agent-atomic)
// ops; ordering via per-wave s_waitcnt vmcnt(0) before the per-wave flag store.
// No cache fences anywhere in the loop.
__global__ __launch_bounds__(256) void rnn_scan_k(
    const f16* __restrict__ whh2, const f16* __restrict__ xp2,
    f16* __restrict__ hbuf, uint* __restrict__ flags)
{
  __shared__ f16 hlds[MB * H_DIM];   // 32 KB, XOR-swizzled
  const int tid = threadIdx.x;
  const int l   = tid & 63;
  const int w   = tid >> 6;
  const int bid = blockIdx.x;        // 0..63
  const int xcd = bid & 7;
  const int g    = xcd >> 1;                       // batch group 0..3
  const int slot = ((bid >> 3) << 1) | (xcd & 1);  // j-slice 0..15
  const int j0   = slot * NJ + w * 16;             // wave's global j base
  const int c     = l & 15;                        // output col within 16
  const int brow0 = (l >> 4) << 2;                 // output row base

  // persistent W fragments: lane l row (j0+c), k = kt*32 + 8*(l>>4) + e
  half8 wf[32];
  {
    const f16* wp = whh2 + (size_t)(j0 + c) * H_DIM + ((l >> 4) << 3);
#pragma unroll
    for (int kt = 0; kt < 32; ++kt) wf[kt] = *(const half8*)(wp + kt * 32);
  }

  f16* hb0 = hbuf + (size_t)g * (2 * MB * H_DIM);
  uint* gflags = flags + g * 64;                   // 64 wave-flags per group
  const int myflag = slot * 4 + w;
  const uint roff = (uint)c * 2048 + ((uint)(l >> 4) << 4);
  const uint rswz = ((uint)c & 7) << 4;
  char* hldsc = (char*)hlds;

  for (int t = 0; t < NSEQ; ++t) {
    const f16* hcur = hb0 + (t & 1) * (MB * H_DIM);
    uint* hnxt32 = (uint*)(hb0 + ((t + 1) & 1) * (MB * H_DIM));

    // prefetch xp_t (plain cached loads; overlaps flag poll)
    const f16* xpb = xp2 + ((size_t)t * NBATCH + g * MB + brow0) * H_DIM + (j0 + c);
    f16 x0 = xpb[0];
    f16 x1 = xpb[H_DIM];
    f16 x2 = xpb[2 * H_DIM];
    f16 x3 = xpb[3 * H_DIM];

    f32x4_t acc;
    acc[0] = (float)x0; acc[1] = (float)x1; acc[2] = (float)x2; acc[3] = (float)x3;

    if (t > 0) {
      // ---- wait for all 64 producer waves of this group to finish step t-1
      if (w == 0) {
        while (true) {
          uint v = __hip_atomic_load(&gflags[l], __ATOMIC_RELAXED, __HIP_MEMORY_SCOPE_AGENT);
          if (__all((int)(v >= (uint)t))) break;
        }
      }
      __syncthreads();   // releases WG; also WAR-protects hlds vs prev reads

      // ---- stage h_t -> LDS via L2-bypassing loads (data lives at L3)
      uint32x4 sv[8];
#pragma unroll
      for (int q = 0; q < 8; ++q) {
        const char* p = (const char*)hcur + (size_t)(q * 256 + tid) * 16;
        asm volatile("global_load_dwordx4 %0, %1, off sc0 sc1"
                     : "=v"(sv[q]) : "v"(p) : "memory");
      }
      asm volatile("s_waitcnt vmcnt(0)" ::: "memory");
      __builtin_amdgcn_sched_barrier(0);
#pragma unroll
      for (int q = 0; q < 8; ++q) {
        uint boff = (uint)(q * 256 + tid) * 16;
        uint row = boff >> 11;
        *(uint32x4*)(hldsc + (boff ^ ((row & 7) << 4))) = sv[q];
      }
      __syncthreads();

      // ---- h_t @ W^T accumulate
#pragma unroll
      for (int kt = 0; kt < 32; ++kt) {
        half8 af = *(const half8*)(hldsc + ((roff + (uint)kt * 64) ^ rswz));
        acc = __builtin_amdgcn_mfma_f32_16x16x32_f16(af, wf[kt], acc, 0, 0, 0);
      }
    }
    // t == 0: h0 = 0  ->  h1 = tanh(xp_0); no stage/MFMA needed.

    // ---- tanh, pack pairs of f16, store via agent-scope atomics (to L3)
    uint st[4];
#pragma unroll
    for (int i = 0; i < 4; ++i) {
      float pre = acc[i];
      float e = __expf(2.0f * pre);
      float th = 1.0f - 2.0f / (e + 1.0f);
      f16 hf = (f16)th;
      uint myv = (uint)__builtin_bit_cast(unsigned short, hf);
      uint pv = __shfl_xor(myv, 1, 64);
      st[i] = myv | (pv << 16);          // valid on even-c lanes: (c, c+1)
    }
    if ((c & 1) == 0) {
#pragma unroll
      for (int i = 0; i < 4; ++i) {
        uint idx = (uint)(brow0 + i) * 512 + (uint)((j0 + c) >> 1);
        __hip_atomic_store(hnxt32 + idx, st[i], __ATOMIC_RELAXED, __HIP_MEMORY_SCOPE_AGENT);
      }
    }
    // all h stores acked at coherence point, then publish per-wave flag
    asm volatile("s_waitcnt vmcnt(0)" ::: "memory");
    if (l == 0) {
      __hip_atomic_store(&gflags[myflag], (uint)(t + 1), __ATOMIC_RELAXED, __HIP_MEMORY_SCOPE_AGENT);
    }
  }
}

// ---------------- out = h_final @ W_fc^T + b_fc ----------------
__global__ __launch_bounds__(64) void fc_out_k(
    const f16* __restrict__ hbuf, const f16* __restrict__ wfc2,
    const float* __restrict__ bfc, float* __restrict__ out)
{
  const int l = threadIdx.x;
  const int wg = blockIdx.x;            // 0..127
  const int m0 = wg & 3;                // batch group
  const int n0 = (wg >> 2) << 4;        // output col base
  const f16* ap = hbuf + (size_t)m0 * (2 * MB * H_DIM)   // buf0 = final h
                  + (size_t)(l & 15) * H_DIM + ((l >> 4) << 3);
  const f16* bp = wfc2 + (size_t)(n0 + (l & 15)) * H_DIM + ((l >> 4) << 3);
  f32x4_t acc;
  float bv = bfc[n0 + (l & 15)];
  acc[0] = bv; acc[1] = bv; acc[2] = bv; acc[3] = bv;
#pragma unroll
  for (int kt = 0; kt < 32; ++kt) {
    half8 a = *(const half8*)(ap + kt * 32);
    half8 b = *(const half8*)(bp + kt * 32);
    acc = __builtin_amdgcn_mfma_f32_16x16x32_f16(a, b, acc, 0, 0, 0);
  }
  const int b0 = (m0 << 4) + ((l >> 4) << 2);
  const int o  = n0 + (l & 15);
#pragma unroll
  for (int i = 0; i < 4; ++i) out[(size_t)(b0 + i) * OUT_DIM + o] = acc[i];
}

// ---------------- launch ----------------
extern "C" void kernel_launch(void* const* d_in, const int* in_sizes, int n_in,
                              void* d_out, int out_size, void* d_ws, size_t ws_size,
                              hipStream_t stream) {
  const float* x   = (const float*)d_in[0];
  const float* wih = (const float*)d_in[1];
  const float* whh = (const float*)d_in[2];
  const float* bih = (const float*)d_in[3];
  const float* bhh = (const float*)d_in[4];
  const float* wfc = (const float*)d_in[5];
  const float* bfc = (const float*)d_in[6];
  float* out = (float*)d_out;
  char* ws = (char*)d_ws;

  // workspace layout (~70.4 MB total)
  f16*   xp2  = (f16*)(ws);                                  // 64 MB  [S][B][H] f16
  f16*   whh2 = (f16*)(ws + (size_t)(64 << 20));             // 2 MB
  f16*   wfc2 = (f16*)(ws + (size_t)(66 << 20));             // 1 MB
  float* bsum = (float*)(ws + (size_t)(67 << 20));           // 4 KB
  f16*   hbuf = (f16*)(ws + (size_t)(67 << 20) + 65536);     // 256 KB [4][2][16][1024]
  uint*  flags= (uint*)(ws + (size_t)(67 << 20) + 65536 + 262144); // 1 KB [4][64]

  // zero wave-flags every call (SDMA writes reach DRAM -> visible to sc1 reads)
  hipMemsetAsync(flags, 0, 1024, stream);

  hipLaunchKernelGGL(cvt_f32_f16_k, dim3(1024), dim3(256), 0, stream, whh, whh2, H_DIM * H_DIM);
  hipLaunchKernelGGL(cvt_f32_f16_k, dim3(512),  dim3(256), 0, stream, wfc, wfc2, OUT_DIM * H_DIM);
  hipLaunchKernelGGL(bias_sum_k,    dim3(4),    dim3(256), 0, stream, bih, bhh, bsum);
  hipLaunchKernelGGL(xp_gemm_k,     dim3(256, 8), dim3(256), 0, stream, x, wih, bsum, xp2);
  hipLaunchKernelGGL(rnn_scan_k,    dim3(64),   dim3(256), 0, stream, whh2, xp2, hbuf, flags);
  hipLaunchKernelGGL(fc_out_k,      dim3(128),  dim3(64),  0, stream, hbuf, wfc2, bfc, out);
}